// Round 6
// baseline (3812.717 us; speedup 1.0000x reference)
//
#include <hip/hip_runtime.h>

#define TS 512
#define NB 64
#define FIN 512
#define HD 512
#define HBUF_U64 (NB * HD / 2)   // 16384 u64 per buffer; 4 buffers = 512 KiB in d_ws
#define R_FAST 16                // dwordx4 fast poll rounds before proven fallback

typedef short bf16x8 __attribute__((ext_vector_type(8)));
typedef float f32x4 __attribute__((ext_vector_type(4)));
typedef unsigned int u32x4 __attribute__((ext_vector_type(4)));

__device__ __forceinline__ unsigned short f2bf(float f) {
  union { float f; unsigned int i; } v; v.f = f;
  unsigned int r = v.i + 0x7fffu + ((v.i >> 16) & 1u);  // RNE
  return (unsigned short)(r >> 16);
}
__device__ __forceinline__ bf16x8 packv(f32x4 a, f32x4 b) {
  bf16x8 r;
#pragma unroll
  for (int i = 0; i < 4; ++i) r[i] = (short)f2bf(a[i]);
#pragma unroll
  for (int i = 0; i < 4; ++i) r[4 + i] = (short)f2bf(b[i]);
  return r;
}
__device__ __forceinline__ float sigm(float x) { return 1.0f / (1.0f + __expf(-x)); }
__device__ __forceinline__ float tanh_(float x) { return 1.0f - 2.0f / (__expf(2.0f * x) + 1.0f); }

// 16B device-coherent load: sc0 sc1 bypasses L1 AND the (per-XCD, stale-able)
// L2 -- same freshness path as agent-scope atomic loads (round-1 pinned).
// Result registers invalid until caller's s_waitcnt vmcnt(0).
template <int OFF>
__device__ __forceinline__ u32x4 ldx4_dev(const unsigned long long* p) {
  u32x4 v;
  asm volatile("global_load_dwordx4 %0, %1, off offset:%2 sc0 sc1"
               : "=v"(v) : "v"(p), "i"(OFF));
  return v;
}

// Persistent fused LSTM. fp32 in, fp32 out, bf16 MFMA internal.
// ROUND-6: 128 WGs x 512 threads (was 256x256) -- halves producer fan-in.
// Island bg = wg&3 (16 batches); hg = wg>>2 (0..31) owns 16 hid dims
// -> 64 gate rows. Wave w=tid>>6: m=w>>2 (0:x@W_ih, 1:h@W_hh),
// kh=(w>>1)&1 (K half), ch=w&1 (gate pair {2ch,2ch+1}).
// Each wave: bfrag[2][8] bf16 weight fragments (tiles = 2 gates), 16 MFMA/step.
//
// h exchange: tagged u64 {tag=t+1 | 2xbf16}, RELAXED agent atomics, 4 rotating
// buffers, producer-major layout:
//   u64 slot = buf*16384 + (bg*32 + hg)*128 + cb*8 + (cj>>1)
// Producer publish = 1 KiB contiguous (~16 lines vs round-5's ~8x64B... 2x
// fewer, fatter transactions). Consumer h-wave (m=1) lane (nloc,quad), MFMA
// step kk needs h[mb0+nloc][kh*256+kk*32+quad*8+e], e=0..7 -> producer
// hg_p = kh*16 + kk*2 + (quad>>1), u64s j = (quad&1)*4 + {0..3}:
//   slot = S0 + kk*256 + j,  S0 = bg*4096+kh*2048+(quad>>1)*128+nloc*8+(quad&1)*4
// Fully dense poll instructions (64 lanes x 16B contiguous). Per-wave fan-in
// = 16 producers (was 32). Merged detect+fetch fast rounds + per-u64 tags +
// proven atomic-u64 fallback, all structure-identical to the 2262us kernel.
__global__ void __launch_bounds__(512, 1) lstm_persist(
    const float* __restrict__ seq,
    const float* __restrict__ w_ih,
    const float* __restrict__ w_hh,
    const float* __restrict__ b_ih,
    const float* __restrict__ b_hh,
    float* __restrict__ out,
    unsigned long long* __restrict__ hbuf)  // [4][16384] tagged u64 in d_ws
{
  const int wg   = blockIdx.x;
  const int bg   = wg & 3;          // island: batches [bg*16,+16)
  const int hg   = wg >> 2;         // 0..31: hid dims [hg*16,+16)
  const int tid  = threadIdx.x;
  const int w    = tid >> 6;        // wave 0..7
  const int lane = tid & 63;
  const int m    = w >> 2;          // 0: x-proj, 1: h-proj
  const int kh   = (w >> 1) & 1;    // K half
  const int ch   = w & 1;           // gate pair {2ch, 2ch+1}
  const int mb0  = bg * 16;
  const int hid0 = hg * 16;
  const int nloc = lane & 15;       // A: m(batch). B: n(col). D: col = n.
  const int quad = lane >> 4;       // A/B: k-chunk. D: row block (batch).
  const int k0   = kh * 256;

  __shared__ __align__(16) float gred[2][8][32][20];  // [t&1][wave][n][m+pad] 40KiB

  const float* W = (m == 0) ? w_ih : w_hh;

  // ---- step-invariant weight fragments -> bf16 registers ----
  bf16x8 bfrag[2][8];  // [tile=gate ch*2+nt][kiter]
#pragma unroll
  for (int nt = 0; nt < 2; ++nt) {
    int grow = (ch * 2 + nt) * HD + hid0 + nloc;  // gate row
    const float* src = W + (size_t)grow * FIN + k0 + quad * 8;
#pragma unroll
    for (int kk = 0; kk < 8; ++kk)
      bfrag[nt][kk] = packv(*(const f32x4*)(src + kk * 32),
                            *(const f32x4*)(src + kk * 32 + 4));
  }

  // ---- cell-thread state (tid<256 = x-waves: one (batch,hid) cell each) ----
  float bias_[4] = {0.f, 0.f, 0.f, 0.f};
  float cprev = 0.0f;
  int cb = 0, cj = 0;
  if (tid < 256) {
    cb = tid >> 4;    // local batch 0..15
    cj = tid & 15;    // local hid 0..15
#pragma unroll
    for (int g = 0; g < 4; ++g) {
      int r = g * HD + hid0 + cj;
      bias_[g] = b_ih[r] + b_hh[r];
    }
  }

  const size_t ax_base = (size_t)(mb0 + nloc) * FIN + k0 + quad * 8;
  // consumer per-lane u64 base within one rotation buffer (h-waves)
  const int rd_base = bg * 4096 + kh * 2048 + (quad >> 1) * 128 + nloc * 8 +
                      (quad & 1) * 4;
  // producer slot base within one rotation buffer
  const int wr_base = (bg * 32 + hg) * 128;

  // ---- software-prefetch x(0) into registers (x-waves) ----
  f32x4 xpf[16];
  if (m == 0) {
    const float* ap = seq + ax_base;
#pragma unroll
    for (int kk = 0; kk < 8; ++kk) {
      xpf[2 * kk]     = *(const f32x4*)(ap + kk * 32);
      xpf[2 * kk + 1] = *(const f32x4*)(ap + kk * 32 + 4);
    }
  }

  for (int t = 0; t < TS; ++t) {
    f32x4 acc0 = {0.f, 0.f, 0.f, 0.f};
    f32x4 acc1 = {0.f, 0.f, 0.f, 0.f};

    if (m == 0) {
      // x-projection from prefetched regs; no cross-WG dependency
      bf16x8 afr[8];
#pragma unroll
      for (int kk = 0; kk < 8; ++kk) afr[kk] = packv(xpf[2 * kk], xpf[2 * kk + 1]);
#pragma unroll
      for (int kk = 0; kk < 8; ++kk) {
        acc0 = __builtin_amdgcn_mfma_f32_16x16x32_bf16(afr[kk], bfrag[0][kk], acc0, 0, 0, 0);
        acc1 = __builtin_amdgcn_mfma_f32_16x16x32_bf16(afr[kk], bfrag[1][kk], acc1, 0, 0, 0);
      }
      // prefetch x(t+1) (lands during the rest of this step)
      int tn = (t + 1 < TS) ? t + 1 : TS - 1;
      const float* ap = seq + (size_t)tn * (NB * FIN) + ax_base;
#pragma unroll
      for (int kk = 0; kk < 8; ++kk) {
        xpf[2 * kk]     = *(const f32x4*)(ap + kk * 32);
        xpf[2 * kk + 1] = *(const f32x4*)(ap + kk * 32 + 4);
      }
    } else if (t > 0) {
      // gather tagged h(t-1): merged detect+fetch polling, producer-major.
      // Pair p: kk = p>>1, u64s S0 + kk*256 + (p&1)*2 + {0,1}.
      const unsigned long long* hb =
          hbuf + (size_t)((t - 1) & 3) * HBUF_U64 + rd_base;
      unsigned long long hv[32];
      unsigned int pend = 0xffffu;  // 16 pending pairs

      for (int r = 0; r < R_FAST && pend; ++r) {
        u32x4 wv[16];
#define ISSUE(p) if (pend & (1u << (p))) \
          wv[p] = ldx4_dev<(((p) & 1) * 16)>(hb + ((p) >> 1) * 256);
        ISSUE(0)  ISSUE(1)  ISSUE(2)  ISSUE(3)
        ISSUE(4)  ISSUE(5)  ISSUE(6)  ISSUE(7)
        ISSUE(8)  ISSUE(9)  ISSUE(10) ISSUE(11)
        ISSUE(12) ISSUE(13) ISSUE(14) ISSUE(15)
#undef ISSUE
        asm volatile("s_waitcnt vmcnt(0)" ::: "memory");
        __builtin_amdgcn_sched_barrier(0);  // rule 18: no use hoisted above wait
#pragma unroll
        for (int p = 0; p < 16; ++p)
          if (pend & (1u << p)) {
            int i0 = (p >> 1) * 4 + (p & 1) * 2;
            unsigned long long a =
                ((unsigned long long)wv[p][1] << 32) | wv[p][0];
            unsigned long long b =
                ((unsigned long long)wv[p][3] << 32) | wv[p][2];
            if ((int)(unsigned int)(a >> 32) >= t &&
                (int)(unsigned int)(b >> 32) >= t) {
              hv[i0] = a; hv[i0 + 1] = b;
              pend &= ~(1u << p);
            }
          }
      }
      if (pend) {
        // proven fallback: per-u64 agent atomics (same addresses)
        unsigned int done = 0;
#pragma unroll
        for (int p = 0; p < 16; ++p)
          if (!(pend & (1u << p)))
            done |= 3u << ((p >> 1) * 4 + (p & 1) * 2);
        for (int r = 0; r < 8192 && done != 0xffffffffu; ++r) {
#pragma unroll
          for (int i = 0; i < 32; ++i)
            if (!((done >> i) & 1u))
              hv[i] = __hip_atomic_load(hb + ((i >> 2) * 256 + (i & 3)),
                                        __ATOMIC_RELAXED, __HIP_MEMORY_SCOPE_AGENT);
          unsigned int nd = done;
#pragma unroll
          for (int i = 0; i < 32; ++i)
            if (!((nd >> i) & 1u) && (int)(unsigned int)(hv[i] >> 32) >= t)
              nd |= 1u << i;
          done = nd;
          if (done != 0xffffffffu) __builtin_amdgcn_s_sleep(1);
        }
      }

      bf16x8 afr[8];
#pragma unroll
      for (int kk = 0; kk < 8; ++kk) {
        union { unsigned int d[4]; bf16x8 v; } u;
#pragma unroll
        for (int j = 0; j < 4; ++j) u.d[j] = (unsigned int)hv[kk * 4 + j];
        afr[kk] = u.v;
      }
#pragma unroll
      for (int kk = 0; kk < 8; ++kk) {
        acc0 = __builtin_amdgcn_mfma_f32_16x16x32_bf16(afr[kk], bfrag[0][kk], acc0, 0, 0, 0);
        acc1 = __builtin_amdgcn_mfma_f32_16x16x32_bf16(afr[kk], bfrag[1][kk], acc1, 0, 0, 0);
      }
    }
    // D layout: col = lane&15 (= n), row = quad*4 + reg (= batch)
    *(f32x4*)&gred[t & 1][w][nloc][quad * 4]      = acc0;
    *(f32x4*)&gred[t & 1][w][16 + nloc][quad * 4] = acc1;
    __syncthreads();  // the only barrier per step (gred is double-buffered)

    if (tid < 256) {
      // gate g lives in waves {g>>1, 2+(g>>1), 4+(g>>1), 6+(g>>1)}, col (g&1)*16+cj
      float gs[4];
#pragma unroll
      for (int g = 0; g < 4; ++g) {
        int wv0 = g >> 1;
        int n   = (g & 1) * 16 + cj;
        gs[g] = bias_[g] + gred[t & 1][wv0][n][cb] + gred[t & 1][wv0 + 2][n][cb] +
                gred[t & 1][wv0 + 4][n][cb] + gred[t & 1][wv0 + 6][n][cb];
      }
      float ig = sigm(gs[0]);
      float fg = sigm(gs[1]);
      float gg = tanh_(gs[2]);
      float og = sigm(gs[3]);
      float c  = fg * cprev + ig * gg;
      cprev = c;
      float h  = og * tanh_(c);
      size_t o = (size_t)t * (NB * HD) + (size_t)(mb0 + cb) * HD + hid0 + cj;
      // publish tagged h pair FIRST: even thread packs (cj, cj+1).
      // 1 KiB contiguous per WG per step.
      unsigned int hu = (unsigned int)f2bf(h);
      unsigned int ho = __shfl_down(hu, 1);
      if ((tid & 1) == 0) {
        unsigned long long tv =
            ((unsigned long long)(unsigned int)(t + 1) << 32) |
            (unsigned long long)(hu | (ho << 16));
        __hip_atomic_store(hbuf + (size_t)(t & 3) * HBUF_U64 + wr_base +
                               cb * 8 + (cj >> 1), tv,
                           __ATOMIC_RELAXED, __HIP_MEMORY_SCOPE_AGENT);
      }
      out[o] = h;
      out[(size_t)TS * NB * HD + o] = c;
    }
    // no second barrier: next step's gred writes hit buffer (t+1)&1
  }
}

extern "C" void kernel_launch(void* const* d_in, const int* in_sizes, int n_in,
                              void* d_out, int out_size, void* d_ws, size_t ws_size,
                              hipStream_t stream) {
  const float* seq = (const float*)d_in[0];
  const float* wih = (const float*)d_in[1];
  const float* whh = (const float*)d_in[2];
  const float* bih = (const float*)d_in[3];
  const float* bhh = (const float*)d_in[4];
  float* out = (float*)d_out;
  unsigned long long* hbuf = (unsigned long long*)d_ws;  // 4*16384*8 = 512 KiB
  hipLaunchKernelGGL(lstm_persist, dim3(128), dim3(512), 0, stream,
                     seq, wih, whh, bih, bhh, out, hbuf);
}

// Round 9
// 2605.262 us; speedup vs baseline: 1.4635x; 1.4635x over previous
//
#include <hip/hip_runtime.h>

#define TS 512
#define NB 64
#define FIN 512
#define HD 512
#define HBUF_U64 (NB * HD / 2)   // 16384 u64 per buffer; 4 buffers = 512 KiB in d_ws
#define R_FAST 16                // dwordx4 fast poll rounds before proven fallback

typedef short bf16x8 __attribute__((ext_vector_type(8)));
typedef float f32x4 __attribute__((ext_vector_type(4)));
typedef unsigned int u32x4 __attribute__((ext_vector_type(4)));

__device__ __forceinline__ unsigned short f2bf(float f) {
  union { float f; unsigned int i; } v; v.f = f;
  unsigned int r = v.i + 0x7fffu + ((v.i >> 16) & 1u);  // RNE
  return (unsigned short)(r >> 16);
}
__device__ __forceinline__ bf16x8 packv(f32x4 a, f32x4 b) {
  bf16x8 r;
#pragma unroll
  for (int i = 0; i < 4; ++i) r[i] = (short)f2bf(a[i]);
#pragma unroll
  for (int i = 0; i < 4; ++i) r[4 + i] = (short)f2bf(b[i]);
  return r;
}
__device__ __forceinline__ float sigm(float x) { return 1.0f / (1.0f + __expf(-x)); }
__device__ __forceinline__ float tanh_(float x) { return 1.0f - 2.0f / (__expf(2.0f * x) + 1.0f); }

// 16B device-coherent load: sc0 sc1 bypasses L1 AND the (per-XCD, stale-able)
// L2 -- same freshness path as agent-scope atomic loads (round-1 pinned).
// Result registers invalid until caller's s_waitcnt vmcnt(0).
template <int OFF>
__device__ __forceinline__ u32x4 ldx4_dev(const unsigned long long* p) {
  u32x4 v;
  asm volatile("global_load_dwordx4 %0, %1, off offset:%2 sc0 sc1"
               : "=v"(v) : "v"(p), "i"(OFF));
  return v;
}

// Persistent fused LSTM. fp32 in, fp32 out, bf16 MFMA internal.
// ROUND-9 = round-8 resubmitted verbatim (round-8 was an infra failure:
// container acquisition died twice before pytest; same as round 4 -> 5).
// Grid: 128 WGs x 256 thr. WG(bg,hg): bg=wg&3 (16 batches), hg=wg>>2 (0..31)
// owns 16 hid dims = 64 gate rows. Island = 32 WGs.
// Wave w: kh=w&1 (K half), nh=w>>1 (gate pair {2nh,2nh+1}); each wave does
// BOTH x@W_ih and h@W_hh for its slice: 16 x-MFMAs + poll(fan-in 16
// producers) + 16 h-MFMAs. Gate sum = 2 gred terms (K halves).
// h exchange: tagged u64 {tag=t+1 | 2xbf16}, RELAXED agent atomics, 4 rotating
// buffers, producer-major: slot = buf*16384 + (bg*32+hg)*128 + cb*8 + (cj>>1)
// -> publish = 1 KiB contiguous per WG per step. Consumer lane (nloc,quad),
// MFMA step kk needs h[mb0+nloc][kh*256+kk*32+quad*8+e], e=0..7 -> producer
// hg_p = kh*16 + kk*2 + (quad>>1), cj = (quad&1)*8+e, u64 j = (quad&1)*4+(e>>1):
//   slot = S0 + kk*256 + j,
//   S0 = bg*4096 + kh*2048 + (quad>>1)*128 + nloc*8 + (quad&1)*4
// Max index: 12288+2048+1792+128+120+4+3 = 16383 < 16384. In range.
// Poll: merged detect+fetch dwordx4 fast rounds + per-u64 tags + proven
// atomic-u64 fallback (structure byte-identical to the 2262us kernel).
__global__ void __launch_bounds__(256, 1) lstm_persist(
    const float* __restrict__ seq,
    const float* __restrict__ w_ih,
    const float* __restrict__ w_hh,
    const float* __restrict__ b_ih,
    const float* __restrict__ b_hh,
    float* __restrict__ out,
    unsigned long long* __restrict__ hbuf)  // [4][16384] tagged u64 in d_ws
{
  const int wg   = blockIdx.x;      // 0..127
  const int bg   = wg & 3;          // island: batches [bg*16,+16)
  const int hg   = wg >> 2;         // 0..31: hid dims [hg*16,+16)
  const int tid  = threadIdx.x;
  const int w    = tid >> 6;        // wave 0..3
  const int lane = tid & 63;
  const int kh   = w & 1;           // K half
  const int nh   = w >> 1;          // gate pair {2nh, 2nh+1}
  const int mb0  = bg * 16;
  const int hid0 = hg * 16;
  const int nloc = lane & 15;       // A: m(batch). B: n(col). D: col = n.
  const int quad = lane >> 4;       // A/B: k-chunk. D: row block (batch).
  const int k0   = kh * 256;

  __shared__ __align__(16) float gred[2][2][64][20];  // [t&1][kh][row][batch+pad]

  // ---- step-invariant weight fragments -> bf16 registers (x AND h) ----
  bf16x8 bfx[2][8], bfh[2][8];  // [ntile=gate 2nh+nt][kiter]
#pragma unroll
  for (int nt = 0; nt < 2; ++nt) {
    int grow = (2 * nh + nt) * HD + hid0 + nloc;  // gate row in 4H space
    const float* sx = w_ih + (size_t)grow * FIN + k0 + quad * 8;
    const float* sh = w_hh + (size_t)grow * HD + k0 + quad * 8;
#pragma unroll
    for (int kk = 0; kk < 8; ++kk) {
      bfx[nt][kk] = packv(*(const f32x4*)(sx + kk * 32),
                          *(const f32x4*)(sx + kk * 32 + 4));
      bfh[nt][kk] = packv(*(const f32x4*)(sh + kk * 32),
                          *(const f32x4*)(sh + kk * 32 + 4));
    }
  }

  // ---- cell-thread state: ALL 256 threads own one (batch,hid) cell ----
  const int cb = tid >> 4;   // local batch 0..15
  const int cj = tid & 15;   // local hid 0..15
  float bias_[4];
#pragma unroll
  for (int g = 0; g < 4; ++g) {
    int r = g * HD + hid0 + cj;
    bias_[g] = b_ih[r] + b_hh[r];
  }
  float cprev = 0.0f;

  const size_t ax_base = (size_t)(mb0 + nloc) * FIN + k0 + quad * 8;
  // consumer per-lane u64 base within one rotation buffer
  const int rd_base = bg * 4096 + kh * 2048 + (quad >> 1) * 128 + nloc * 8 +
                      (quad & 1) * 4;
  // producer slot base within one rotation buffer
  const int wr_base = (bg * 32 + hg) * 128;

  // ---- software-prefetch x(0) into registers (all waves) ----
  f32x4 xpf[16];
  {
    const float* ap = seq + ax_base;
#pragma unroll
    for (int kk = 0; kk < 8; ++kk) {
      xpf[2 * kk]     = *(const f32x4*)(ap + kk * 32);
      xpf[2 * kk + 1] = *(const f32x4*)(ap + kk * 32 + 4);
    }
  }

  for (int t = 0; t < TS; ++t) {
    f32x4 acc0 = {0.f, 0.f, 0.f, 0.f};
    f32x4 acc1 = {0.f, 0.f, 0.f, 0.f};

    // ---- x-projection from prefetched regs (no cross-WG dependency) ----
    {
      bf16x8 afr[8];
#pragma unroll
      for (int kk = 0; kk < 8; ++kk) afr[kk] = packv(xpf[2 * kk], xpf[2 * kk + 1]);
#pragma unroll
      for (int kk = 0; kk < 8; ++kk) {
        acc0 = __builtin_amdgcn_mfma_f32_16x16x32_bf16(afr[kk], bfx[0][kk], acc0, 0, 0, 0);
        acc1 = __builtin_amdgcn_mfma_f32_16x16x32_bf16(afr[kk], bfx[1][kk], acc1, 0, 0, 0);
      }
      // prefetch x(t+1): in flight during the poll (latencies overlap)
      int tn = (t + 1 < TS) ? t + 1 : TS - 1;
      const float* ap = seq + (size_t)tn * (NB * FIN) + ax_base;
#pragma unroll
      for (int kk = 0; kk < 8; ++kk) {
        xpf[2 * kk]     = *(const f32x4*)(ap + kk * 32);
        xpf[2 * kk + 1] = *(const f32x4*)(ap + kk * 32 + 4);
      }
    }

    if (t > 0) {
      // ---- gather tagged h(t-1): merged detect+fetch, producer-major ----
      // Pair p (0..15): kk = p>>1, u64s S0 + kk*256 + (p&1)*2 + {0,1}.
      const unsigned long long* hb =
          hbuf + (size_t)((t - 1) & 3) * HBUF_U64 + rd_base;
      unsigned long long hv[32];
      unsigned int pend = 0xffffu;  // 16 pending pairs

      for (int r = 0; r < R_FAST && pend; ++r) {
        u32x4 wv[16];
#define ISSUE(p) if (pend & (1u << (p))) \
          wv[p] = ldx4_dev<((((p) >> 1) & 1) * 2048 + ((p) & 1) * 16)>( \
              hb + ((p) >> 2) * 512);
        ISSUE(0)  ISSUE(1)  ISSUE(2)  ISSUE(3)
        ISSUE(4)  ISSUE(5)  ISSUE(6)  ISSUE(7)
        ISSUE(8)  ISSUE(9)  ISSUE(10) ISSUE(11)
        ISSUE(12) ISSUE(13) ISSUE(14) ISSUE(15)
#undef ISSUE
        asm volatile("s_waitcnt vmcnt(0)" ::: "memory");
        __builtin_amdgcn_sched_barrier(0);  // rule 18: no use hoisted above wait
#pragma unroll
        for (int p = 0; p < 16; ++p)
          if (pend & (1u << p)) {
            int i0 = (p >> 1) * 4 + (p & 1) * 2;
            unsigned long long a =
                ((unsigned long long)wv[p][1] << 32) | wv[p][0];
            unsigned long long b =
                ((unsigned long long)wv[p][3] << 32) | wv[p][2];
            if ((int)(unsigned int)(a >> 32) >= t &&
                (int)(unsigned int)(b >> 32) >= t) {
              hv[i0] = a; hv[i0 + 1] = b;
              pend &= ~(1u << p);
            }
          }
      }
      if (pend) {
        // proven fallback: per-u64 agent atomics (same addresses)
        unsigned int done = 0;
#pragma unroll
        for (int p = 0; p < 16; ++p)
          if (!(pend & (1u << p)))
            done |= 3u << ((p >> 1) * 4 + (p & 1) * 2);
        for (int r = 0; r < 8192 && done != 0xffffffffu; ++r) {
#pragma unroll
          for (int i = 0; i < 32; ++i)
            if (!((done >> i) & 1u))
              hv[i] = __hip_atomic_load(hb + ((i >> 2) * 256 + (i & 3)),
                                        __ATOMIC_RELAXED, __HIP_MEMORY_SCOPE_AGENT);
          unsigned int nd = done;
#pragma unroll
          for (int i = 0; i < 32; ++i)
            if (!((nd >> i) & 1u) && (int)(unsigned int)(hv[i] >> 32) >= t)
              nd |= 1u << i;
          done = nd;
          if (done != 0xffffffffu) __builtin_amdgcn_s_sleep(1);
        }
      }

      bf16x8 afr[8];
#pragma unroll
      for (int kk = 0; kk < 8; ++kk) {
        union { unsigned int d[4]; bf16x8 v; } u;
#pragma unroll
        for (int j = 0; j < 4; ++j) u.d[j] = (unsigned int)hv[kk * 4 + j];
        afr[kk] = u.v;
      }
#pragma unroll
      for (int kk = 0; kk < 8; ++kk) {
        acc0 = __builtin_amdgcn_mfma_f32_16x16x32_bf16(afr[kk], bfh[0][kk], acc0, 0, 0, 0);
        acc1 = __builtin_amdgcn_mfma_f32_16x16x32_bf16(afr[kk], bfh[1][kk], acc1, 0, 0, 0);
      }
    }

    // D layout: col = lane&15 (= n), row = quad*4 + reg (= batch)
    *(f32x4*)&gred[t & 1][kh][nh * 32 + nloc][quad * 4]      = acc0;
    *(f32x4*)&gred[t & 1][kh][nh * 32 + 16 + nloc][quad * 4] = acc1;
    __syncthreads();  // the only barrier per step (gred is double-buffered)

    // ---- cell update: all 256 threads (one cell each) ----
    {
      float gs[4];
#pragma unroll
      for (int g = 0; g < 4; ++g) {
        int n = g * 16 + cj;  // WG-local gate row
        gs[g] = bias_[g] + gred[t & 1][0][n][cb] + gred[t & 1][1][n][cb];
      }
      float ig = sigm(gs[0]);
      float fg = sigm(gs[1]);
      float gg = tanh_(gs[2]);
      float og = sigm(gs[3]);
      float c  = fg * cprev + ig * gg;
      cprev = c;
      float h  = og * tanh_(c);
      size_t o = (size_t)t * (NB * HD) + (size_t)(mb0 + cb) * HD + hid0 + cj;
      // publish tagged h pair FIRST: even thread packs (cj, cj+1).
      // 1 KiB contiguous per WG per step.
      unsigned int hu = (unsigned int)f2bf(h);
      unsigned int ho = __shfl_down(hu, 1);
      if ((tid & 1) == 0) {  // cj even
        unsigned long long tv =
            ((unsigned long long)(unsigned int)(t + 1) << 32) |
            (unsigned long long)(hu | (ho << 16));
        __hip_atomic_store(hbuf + (size_t)(t & 3) * HBUF_U64 + wr_base +
                               cb * 8 + (cj >> 1), tv,
                           __ATOMIC_RELAXED, __HIP_MEMORY_SCOPE_AGENT);
      }
      out[o] = h;
      out[(size_t)TS * NB * HD + o] = c;
    }
    // no second barrier: next step's gred writes hit buffer (t+1)&1
  }
}

extern "C" void kernel_launch(void* const* d_in, const int* in_sizes, int n_in,
                              void* d_out, int out_size, void* d_ws, size_t ws_size,
                              hipStream_t stream) {
  const float* seq = (const float*)d_in[0];
  const float* wih = (const float*)d_in[1];
  const float* whh = (const float*)d_in[2];
  const float* bih = (const float*)d_in[3];
  const float* bhh = (const float*)d_in[4];
  float* out = (float*)d_out;
  unsigned long long* hbuf = (unsigned long long*)d_ws;  // 4*16384*8 = 512 KiB
  hipLaunchKernelGGL(lstm_persist, dim3(128), dim3(256), 0, stream,
                     seq, wih, whh, bih, bhh, out, hbuf);
}